// Round 5
// baseline (4046.205 us; speedup 1.0000x reference)
//
#include <hip/hip_runtime.h>

#define N_USERS 100000
#define N_ITEMS 50000
#define N_NODES 150000
#define DIM 32
#define N_EDGES 8000000
#define B_OUT 65536

#define NB 1024                      // row buckets
#define RPB 147                      // rows per bucket (1024*147 >= 150000)
#define CH 32768                     // edges per chunk
#define N_PBLK ((N_EDGES + CH - 1) / CH)   // 245
#define PART_GRID 96                 // persistent blocks; 12/XCD * 256KB = 3MB dirty frontier per XCD
#define PART_T 1024
#define SPMM_T 256

// ---------------------------------------------------------------------------
// x_a = concat(user_emb, item_emb); emb_sum = same.
// ---------------------------------------------------------------------------
__global__ void init_kernel(const float* __restrict__ user_emb,
                            const float* __restrict__ item_emb,
                            float* __restrict__ x_a,
                            float* __restrict__ emb_sum) {
    int i = blockIdx.x * blockDim.x + threadIdx.x;   // float4 index
    const int total = N_NODES * DIM / 4;
    if (i >= total) return;
    const int user_f4 = N_USERS * DIM / 4;
    float4 v;
    if (i < user_f4) v = ((const float4*)user_emb)[i];
    else             v = ((const float4*)item_emb)[i - user_f4];
    ((float4*)x_a)[i]     = v;
    ((float4*)emb_sum)[i] = v;
}

// ---------------------------------------------------------------------------
// Partition, persistent blocks. For each 32K-edge chunk:
//   pass1: LDS bucket histogram
//   scan : LDS exclusive scan (1 bin/thread) -> run starts; writes directory
//          runstartT[b][chunk] = chunk*CH + excl[b]  (row NB = chunk end)
//   pass2: rank via LDS cursor atomics, write payload into the chunk's OWN
//          contiguous region bucket-sorted. All writes confined to 256KB.
// Payload: int2{ (row_local<<18)|col , val_bits }.
// ---------------------------------------------------------------------------
__global__ void __launch_bounds__(PART_T)
part_kernel(const int* __restrict__ rows,
            const int* __restrict__ cols,
            const float* __restrict__ vals,
            int* __restrict__ runstartT,
            int2* __restrict__ bucket_ev) {
    __shared__ int hist[NB];
    const int tid = threadIdx.x;

    for (int chunk = blockIdx.x; chunk < N_PBLK; chunk += PART_GRID) {
        const int e0   = chunk * CH;
        const int ecnt = (N_EDGES - e0 < CH) ? (N_EDGES - e0) : CH;

        hist[tid] = 0;
        __syncthreads();
        // pass1: histogram
        for (int j = tid; j < ecnt; j += PART_T)
            atomicAdd(&hist[(unsigned)rows[e0 + j] / RPB], 1);
        __syncthreads();
        // in-place Hillis-Steele inclusive scan over 1024 bins
        int v = hist[tid];
        for (int off = 1; off < NB; off <<= 1) {
            int t = (tid >= off) ? hist[tid - off] : 0;
            __syncthreads();
            hist[tid] += t;
            __syncthreads();
        }
        int incl = hist[tid];
        int excl = incl - v;
        runstartT[(size_t)tid * N_PBLK + chunk] = e0 + excl;
        if (tid == NB - 1) runstartT[(size_t)NB * N_PBLK + chunk] = e0 + incl;
        hist[tid] = excl;            // becomes cursor
        __syncthreads();
        // pass2: rank + write (rows re-read, L2-hot)
        for (int j = tid; j < ecnt; j += PART_T) {
            int e = e0 + j;
            int r = rows[e];
            unsigned b = (unsigned)r / RPB;
            int k = atomicAdd(&hist[b], 1);
            int2 ev;
            ev.x = (int)(((unsigned)(r - (int)b * RPB) << 18) | (unsigned)cols[e]);
            ev.y = __float_as_int(vals[e]);
            bucket_ev[e0 + k] = ev;
        }
        __syncthreads();
    }
}

// ---------------------------------------------------------------------------
// Bucket SpMM with LDS fp32 accumulation (ds_add_f32). Block b owns rows
// [b*RPB, b*RPB+RPB). Walks its 245 runs via the directory. Half-wave per
// run-stream, lane = dim; 4-deep unroll keeps 4 gathers in flight.
// Fused: emb_sum += acc; optional xout store (skipped on last layer).
// ---------------------------------------------------------------------------
__global__ void spmm_bucket_kernel(const int* __restrict__ runstartT,
                                   const int2* __restrict__ bucket_ev,
                                   const float* __restrict__ xin,
                                   float* __restrict__ xout,
                                   float* __restrict__ emb_sum,
                                   int write_x) {
    __shared__ float acc[RPB * DIM];        // 18816 B
    __shared__ int rs0[N_PBLK];
    __shared__ int rs1[N_PBLK];
    const int b   = blockIdx.x;
    const int tid = threadIdx.x;

    for (int i = tid; i < RPB * DIM; i += SPMM_T) acc[i] = 0.f;
    for (int i = tid; i < N_PBLK; i += SPMM_T) {
        rs0[i] = runstartT[(size_t)b * N_PBLK + i];
        rs1[i] = runstartT[(size_t)(b + 1) * N_PBLK + i];
    }
    __syncthreads();

    const int hw = tid >> 5;    // 8 half-waves
    const int d  = tid & 31;
    for (int c = hw; c < N_PBLK; c += (SPMM_T / 32)) {
        int i = rs0[c];
        const int e = rs1[c];
        for (; i + 4 <= e; i += 4) {
            int2 v0 = bucket_ev[i],     v1 = bucket_ev[i + 1];
            int2 v2 = bucket_ev[i + 2], v3 = bucket_ev[i + 3];
            float x0 = xin[((unsigned)v0.x & 0x3FFFFu) * DIM + d];
            float x1 = xin[((unsigned)v1.x & 0x3FFFFu) * DIM + d];
            float x2 = xin[((unsigned)v2.x & 0x3FFFFu) * DIM + d];
            float x3 = xin[((unsigned)v3.x & 0x3FFFFu) * DIM + d];
            atomicAdd(&acc[(((unsigned)v0.x) >> 18) * DIM + d], __int_as_float(v0.y) * x0);
            atomicAdd(&acc[(((unsigned)v1.x) >> 18) * DIM + d], __int_as_float(v1.y) * x1);
            atomicAdd(&acc[(((unsigned)v2.x) >> 18) * DIM + d], __int_as_float(v2.y) * x2);
            atomicAdd(&acc[(((unsigned)v3.x) >> 18) * DIM + d], __int_as_float(v3.y) * x3);
        }
        for (; i < e; ++i) {
            int2 ev = bucket_ev[i];
            float x = xin[((unsigned)ev.x & 0x3FFFFu) * DIM + d];
            atomicAdd(&acc[(((unsigned)ev.x) >> 18) * DIM + d], __int_as_float(ev.y) * x);
        }
    }
    __syncthreads();

    // writeback: acc layout matches global layout starting at row0*DIM
    const int base = b * RPB * DIM;
    const int lim  = N_NODES * DIM - base;          // may be < RPB*DIM for last bucket
    for (int i = tid; i < RPB * DIM && i < lim; i += SPMM_T) {
        float a = acc[i];
        int o = base + i;
        if (write_x) xout[o] = a;
        emb_sum[o] += a;
    }
}

// ---------------------------------------------------------------------------
// Readout: light = emb_sum/4; gamma = <light_u, light_i>; out = gamma*std+mean.
// ---------------------------------------------------------------------------
__global__ void final_kernel(const int* __restrict__ users,
                             const int* __restrict__ items,
                             const float* __restrict__ emb_sum,
                             const float* __restrict__ means,
                             const float* __restrict__ stds,
                             float* __restrict__ out) {
    int b = blockIdx.x * blockDim.x + threadIdx.x;
    if (b >= B_OUT) return;
    int u  = users[b];
    int it = items[b] + N_USERS;
    const float4* su = (const float4*)(emb_sum + (size_t)u  * DIM);
    const float4* si = (const float4*)(emb_sum + (size_t)it * DIM);
    float gamma = 0.f;
    #pragma unroll
    for (int k = 0; k < DIM / 4; ++k) {
        float4 a = su[k], c = si[k];
        gamma += (a.x * 0.25f) * (c.x * 0.25f) + (a.y * 0.25f) * (c.y * 0.25f)
               + (a.z * 0.25f) * (c.z * 0.25f) + (a.w * 0.25f) * (c.w * 0.25f);
    }
    out[b] = gamma * stds[u] + means[u];
}

extern "C" void kernel_launch(void* const* d_in, const int* in_sizes, int n_in,
                              void* d_out, int out_size, void* d_ws, size_t ws_size,
                              hipStream_t stream) {
    const int*   users    = (const int*)d_in[0];
    const int*   items    = (const int*)d_in[1];
    const int*   rows     = (const int*)d_in[2];
    const int*   cols     = (const int*)d_in[3];
    const float* vals     = (const float*)d_in[4];
    const float* user_emb = (const float*)d_in[5];
    const float* item_emb = (const float*)d_in[6];
    const float* means    = (const float*)d_in[7];
    const float* stds     = (const float*)d_in[8];
    float* out = (float*)d_out;

    char* w = (char*)d_ws;
    size_t off = 0;
    auto alloc = [&](size_t bytes) -> void* {
        void* p = w + off;
        off = (off + bytes + 255) & ~(size_t)255;
        return p;
    };
    int2*  bucket_ev = (int2*)alloc((size_t)N_PBLK * CH * sizeof(int2));        // 64.2 MB
    int*   runstartT = (int*) alloc((size_t)(NB + 1) * N_PBLK * sizeof(int));   // 1.0 MB
    float* x_a       = (float*)alloc((size_t)N_NODES * DIM * sizeof(float));
    float* x_b       = (float*)alloc((size_t)N_NODES * DIM * sizeof(float));
    float* emb_sum   = (float*)alloc((size_t)N_NODES * DIM * sizeof(float));
    (void)ws_size;

    const int T = 256;
    const int g_init  = (N_NODES * DIM / 4 + T - 1) / T;
    const int g_final = (B_OUT + T - 1) / T;

    part_kernel<<<PART_GRID, PART_T, 0, stream>>>(rows, cols, vals, runstartT, bucket_ev);
    init_kernel<<<g_init, T, 0, stream>>>(user_emb, item_emb, x_a, emb_sum);

    spmm_bucket_kernel<<<NB, SPMM_T, 0, stream>>>(runstartT, bucket_ev, x_a, x_b, emb_sum, 1);
    spmm_bucket_kernel<<<NB, SPMM_T, 0, stream>>>(runstartT, bucket_ev, x_b, x_a, emb_sum, 1);
    spmm_bucket_kernel<<<NB, SPMM_T, 0, stream>>>(runstartT, bucket_ev, x_a, x_b, emb_sum, 0);

    final_kernel<<<g_final, T, 0, stream>>>(users, items, emb_sum, means, stds, out);
}

// Round 6
// 765.929 us; speedup vs baseline: 5.2827x; 5.2827x over previous
//
#include <hip/hip_runtime.h>

#define N_USERS 100000
#define N_ITEMS 50000
#define N_NODES 150000
#define DIM 32
#define N_EDGES 8000000
#define B_OUT 65536

#define NB 1024                      // row buckets
#define RPB 147                      // rows per bucket (1024*147 >= 150000)
#define CH 32768                     // edges per chunk
#define N_PBLK ((N_EDGES + CH - 1) / CH)   // 245
#define PART_GRID 96                 // persistent blocks
#define PART_T 1024
#define T 256

__device__ __forceinline__ unsigned short f2bf(float f) {
    unsigned b = __float_as_uint(f);
    return (unsigned short)((b + 0x7FFFu + ((b >> 16) & 1u)) >> 16);   // RNE
}
__device__ __forceinline__ float bf2f(unsigned short u) {
    return __uint_as_float((unsigned)u << 16);
}

// ---------------------------------------------------------------------------
// init: x_a(bf16) = concat(user_emb, item_emb); emb_sum(f32) = same.
// ---------------------------------------------------------------------------
__global__ void init_kernel(const float* __restrict__ user_emb,
                            const float* __restrict__ item_emb,
                            unsigned short* __restrict__ x_a,
                            float* __restrict__ emb_sum) {
    int i = blockIdx.x * blockDim.x + threadIdx.x;   // float4 index
    const int total = N_NODES * DIM / 4;
    if (i >= total) return;
    const int user_f4 = N_USERS * DIM / 4;
    float4 v;
    if (i < user_f4) v = ((const float4*)user_emb)[i];
    else             v = ((const float4*)item_emb)[i - user_f4];
    ((float4*)emb_sum)[i] = v;
    ushort4 h;
    h.x = f2bf(v.x); h.y = f2bf(v.y); h.z = f2bf(v.z); h.w = f2bf(v.w);
    ((ushort4*)x_a)[i] = h;
}

// ---------------------------------------------------------------------------
// Partition, persistent blocks (proven R5): chunk-local bucket sort + run dir.
// Payload: int2{ (row_local<<18)|col , val_bits }.
// ---------------------------------------------------------------------------
__global__ void __launch_bounds__(PART_T)
part_kernel(const int* __restrict__ rows,
            const int* __restrict__ cols,
            const float* __restrict__ vals,
            int* __restrict__ runstartT,
            int2* __restrict__ bucket_ev) {
    __shared__ int hist[NB];
    const int tid = threadIdx.x;

    for (int chunk = blockIdx.x; chunk < N_PBLK; chunk += PART_GRID) {
        const int e0   = chunk * CH;
        const int ecnt = (N_EDGES - e0 < CH) ? (N_EDGES - e0) : CH;

        hist[tid] = 0;
        __syncthreads();
        for (int j = tid; j < ecnt; j += PART_T)
            atomicAdd(&hist[(unsigned)rows[e0 + j] / RPB], 1);
        __syncthreads();
        int v = hist[tid];
        for (int off = 1; off < NB; off <<= 1) {
            int t = (tid >= off) ? hist[tid - off] : 0;
            __syncthreads();
            hist[tid] += t;
            __syncthreads();
        }
        int incl = hist[tid];
        int excl = incl - v;
        runstartT[(size_t)tid * N_PBLK + chunk] = e0 + excl;
        if (tid == NB - 1) runstartT[(size_t)NB * N_PBLK + chunk] = e0 + incl;
        hist[tid] = excl;            // becomes cursor
        __syncthreads();
        for (int j = tid; j < ecnt; j += PART_T) {
            int e = e0 + j;
            int r = rows[e];
            unsigned b = (unsigned)r / RPB;
            int k = atomicAdd(&hist[b], 1);
            int2 ev;
            ev.x = (int)(((unsigned)(r - (int)b * RPB) << 18) | (unsigned)cols[e]);
            ev.y = __float_as_int(vals[e]);
            bucket_ev[e0 + k] = ev;
        }
        __syncthreads();
    }
}

// ---------------------------------------------------------------------------
// Bucket totals -> exclusive scan -> bcsr (CSR base per bucket).
// ---------------------------------------------------------------------------
__global__ void bucket_scan_kernel(const int* __restrict__ runstartT,
                                   int* __restrict__ bcsr,
                                   int* __restrict__ row_ptr) {
    __shared__ int s[NB];
    const int b = threadIdx.x;
    int c = 0;
    for (int ch = 0; ch < N_PBLK; ++ch)
        c += runstartT[(size_t)(b + 1) * N_PBLK + ch]
           - runstartT[(size_t)b * N_PBLK + ch];
    s[b] = c;
    __syncthreads();
    for (int off = 1; off < NB; off <<= 1) {
        int t = (b >= off) ? s[b - off] : 0;
        __syncthreads();
        s[b] += t;
        __syncthreads();
    }
    bcsr[b] = s[b] - c;
    if (b == 0) row_ptr[N_NODES] = N_EDGES;
}

// ---------------------------------------------------------------------------
// Mini-scatter: one block per bucket. Gathers its 245 runs from bucket_ev,
// builds row_ptr for its 147 rows (LDS hist + scan), then LDS-cursor scatter
// -> exact row-sorted CSR. Writes confined to the bucket's CSR span.
// ---------------------------------------------------------------------------
__global__ void mini_scatter_kernel(const int* __restrict__ runstartT,
                                    const int2* __restrict__ bucket_ev,
                                    const int* __restrict__ bcsr,
                                    int* __restrict__ row_ptr,
                                    int2* __restrict__ csr_ev) {
    __shared__ int rs0[N_PBLK];
    __shared__ int rs1[N_PBLK];
    __shared__ int cnt_r[RPB];
    __shared__ int s[T];
    __shared__ int cur[RPB];
    const int b   = blockIdx.x;
    const int tid = threadIdx.x;

    for (int i = tid; i < N_PBLK; i += T) {
        rs0[i] = runstartT[(size_t)b * N_PBLK + i];
        rs1[i] = runstartT[(size_t)(b + 1) * N_PBLK + i];
    }
    if (tid < RPB) cnt_r[tid] = 0;
    __syncthreads();

    const int hw = tid >> 5, lane = tid & 31;
    for (int c = hw; c < N_PBLK; c += (T / 32))
        for (int i = rs0[c] + lane; i < rs1[c]; i += 32)
            atomicAdd(&cnt_r[(unsigned)bucket_ev[i].x >> 18], 1);
    __syncthreads();

    int v = (tid < RPB) ? cnt_r[tid] : 0;
    s[tid] = v;
    __syncthreads();
    for (int off = 1; off < T; off <<= 1) {
        int t = (tid >= off) ? s[tid - off] : 0;
        __syncthreads();
        s[tid] += t;
        __syncthreads();
    }
    const int cb = bcsr[b];
    if (tid < RPB) {
        int excl = cb + s[tid] - v;
        cur[tid] = excl;
        int r = b * RPB + tid;
        if (r < N_NODES) row_ptr[r] = excl;
    }
    __syncthreads();

    for (int c = hw; c < N_PBLK; c += (T / 32))
        for (int i = rs0[c] + lane; i < rs1[c]; i += 32) {
            int2 ev = bucket_ev[i];
            unsigned key = (unsigned)ev.x;
            int pos = atomicAdd(&cur[key >> 18], 1);
            int2 o; o.x = (int)(key & 0x3FFFFu); o.y = ev.y;
            csr_ev[pos] = o;
        }
}

// ---------------------------------------------------------------------------
// CSR SpMM, bf16 gather, f32 accumulate. Half-wave per row, lane = dim.
// Fused: emb_sum += acc; xout(bf16) stored unless last layer.
// ---------------------------------------------------------------------------
__global__ void spmm_kernel(const int* __restrict__ row_ptr,
                            const int2* __restrict__ csr_ev,
                            const unsigned short* __restrict__ xin,
                            unsigned short* __restrict__ xout,
                            float* __restrict__ emb_sum,
                            int write_x) {
    int tid = blockIdx.x * blockDim.x + threadIdx.x;
    int row = tid >> 5;
    int d   = tid & 31;
    if (row >= N_NODES) return;
    int s = row_ptr[row];
    int e = row_ptr[row + 1];
    float acc = 0.f;
    int i = s;
    for (; i + 8 <= e; i += 8) {
        int2 ev[8];
        #pragma unroll
        for (int j = 0; j < 8; ++j) ev[j] = csr_ev[i + j];
        float x[8];
        #pragma unroll
        for (int j = 0; j < 8; ++j)
            x[j] = bf2f(xin[(unsigned)ev[j].x * DIM + d]);
        #pragma unroll
        for (int j = 0; j < 8; ++j)
            acc += __int_as_float(ev[j].y) * x[j];
    }
    for (; i < e; ++i) {
        int2 ev = csr_ev[i];
        acc += __int_as_float(ev.y) * bf2f(xin[(unsigned)ev.x * DIM + d]);
    }
    int o = row * DIM + d;
    if (write_x) xout[o] = f2bf(acc);
    emb_sum[o] += acc;
}

// ---------------------------------------------------------------------------
// Readout.
// ---------------------------------------------------------------------------
__global__ void final_kernel(const int* __restrict__ users,
                             const int* __restrict__ items,
                             const float* __restrict__ emb_sum,
                             const float* __restrict__ means,
                             const float* __restrict__ stds,
                             float* __restrict__ out) {
    int b = blockIdx.x * blockDim.x + threadIdx.x;
    if (b >= B_OUT) return;
    int u  = users[b];
    int it = items[b] + N_USERS;
    const float4* su = (const float4*)(emb_sum + (size_t)u  * DIM);
    const float4* si = (const float4*)(emb_sum + (size_t)it * DIM);
    float gamma = 0.f;
    #pragma unroll
    for (int k = 0; k < DIM / 4; ++k) {
        float4 a = su[k], c = si[k];
        gamma += (a.x * 0.25f) * (c.x * 0.25f) + (a.y * 0.25f) * (c.y * 0.25f)
               + (a.z * 0.25f) * (c.z * 0.25f) + (a.w * 0.25f) * (c.w * 0.25f);
    }
    out[b] = gamma * stds[u] + means[u];
}

extern "C" void kernel_launch(void* const* d_in, const int* in_sizes, int n_in,
                              void* d_out, int out_size, void* d_ws, size_t ws_size,
                              hipStream_t stream) {
    const int*   users    = (const int*)d_in[0];
    const int*   items    = (const int*)d_in[1];
    const int*   rows     = (const int*)d_in[2];
    const int*   cols     = (const int*)d_in[3];
    const float* vals     = (const float*)d_in[4];
    const float* user_emb = (const float*)d_in[5];
    const float* item_emb = (const float*)d_in[6];
    const float* means    = (const float*)d_in[7];
    const float* stds     = (const float*)d_in[8];
    float* out = (float*)d_out;

    char* w = (char*)d_ws;
    size_t off = 0;
    auto alloc = [&](size_t bytes) -> void* {
        void* p = w + off;
        off = (off + bytes + 255) & ~(size_t)255;
        return p;
    };
    // Region A: bucket_ev (live: part -> mini_scatter) aliases
    //           {x_a, x_b, emb_sum} (live: init -> end).
    size_t regionA = ((size_t)N_PBLK * CH * sizeof(int2) + 255) & ~(size_t)255;  // 64.2 MB
    char* a0 = (char*)alloc(regionA);
    int2* bucket_ev = (int2*)a0;
    size_t aoff = 0;
    auto allocA = [&](size_t bytes) -> void* {
        void* p = a0 + aoff;
        aoff = (aoff + bytes + 255) & ~(size_t)255;
        return p;
    };
    unsigned short* x_a     = (unsigned short*)allocA((size_t)N_NODES * DIM * 2);  // 9.6 MB
    unsigned short* x_b     = (unsigned short*)allocA((size_t)N_NODES * DIM * 2);  // 9.6 MB
    float*          emb_sum = (float*)allocA((size_t)N_NODES * DIM * 4);           // 19.2 MB

    int*  runstartT = (int*) alloc((size_t)(NB + 1) * N_PBLK * sizeof(int));   // 1.0 MB
    int*  row_ptr   = (int*) alloc((size_t)(N_NODES + 1) * sizeof(int));
    int*  bcsr      = (int*) alloc((size_t)NB * sizeof(int));
    int2* csr_ev    = (int2*)alloc((size_t)N_EDGES * sizeof(int2));             // 64 MB
    (void)ws_size;

    const int g_init  = (N_NODES * DIM / 4 + T - 1) / T;
    const int g_spmm  = (N_NODES * DIM + T - 1) / T;     // 18750
    const int g_final = (B_OUT + T - 1) / T;

    // --- CSR build ---
    part_kernel<<<PART_GRID, PART_T, 0, stream>>>(rows, cols, vals, runstartT, bucket_ev);
    bucket_scan_kernel<<<1, NB, 0, stream>>>(runstartT, bcsr, row_ptr);
    mini_scatter_kernel<<<NB, T, 0, stream>>>(runstartT, bucket_ev, bcsr, row_ptr, csr_ev);

    // --- dense pipeline (bucket_ev dead from here; region reused) ---
    init_kernel<<<g_init, T, 0, stream>>>(user_emb, item_emb, x_a, emb_sum);
    spmm_kernel<<<g_spmm, T, 0, stream>>>(row_ptr, csr_ev, x_a, x_b, emb_sum, 1);
    spmm_kernel<<<g_spmm, T, 0, stream>>>(row_ptr, csr_ev, x_b, x_a, emb_sum, 1);
    spmm_kernel<<<g_spmm, T, 0, stream>>>(row_ptr, csr_ev, x_a, x_b, emb_sum, 0);

    final_kernel<<<g_final, T, 0, stream>>>(users, items, emb_sum, means, stds, out);
}

// Round 7
// 541.645 us; speedup vs baseline: 7.4702x; 1.4141x over previous
//
#include <hip/hip_runtime.h>

#define N_USERS 100000
#define N_ITEMS 50000
#define N_NODES 150000
#define DIM 32
#define N_EDGES 8000000
#define B_OUT 65536

#define NB 1024                      // row buckets
#define RPB 147                      // rows per bucket (1024*147 >= 150000)
#define CH 32768                     // edges per chunk
#define N_PBLK ((N_EDGES + CH - 1) / CH)   // 245
#define PART_T 1024
#define MS_T 512
#define T 256
#define NRED 8                       // partial-reduce blocks for bucket totals
#define RS_LD (NB + 1)               // runstart leading dim: [chunk][NB+1]

__device__ __forceinline__ unsigned short f2bf(float f) {
    unsigned b = __float_as_uint(f);
    return (unsigned short)((b + 0x7FFFu + ((b >> 16) & 1u)) >> 16);   // RNE
}
__device__ __forceinline__ float bf2f(unsigned short u) {
    return __uint_as_float((unsigned)u << 16);
}

// ---------------------------------------------------------------------------
// init: x_a(bf16) = concat(user_emb, item_emb); emb_sum(f32) = same.
// ---------------------------------------------------------------------------
__global__ void init_kernel(const float* __restrict__ user_emb,
                            const float* __restrict__ item_emb,
                            unsigned short* __restrict__ x_a,
                            float* __restrict__ emb_sum) {
    int i = blockIdx.x * blockDim.x + threadIdx.x;   // float4 index
    const int total = N_NODES * DIM / 4;
    if (i >= total) return;
    const int user_f4 = N_USERS * DIM / 4;
    float4 v;
    if (i < user_f4) v = ((const float4*)user_emb)[i];
    else             v = ((const float4*)item_emb)[i - user_f4];
    ((float4*)emb_sum)[i] = v;
    ushort4 h;
    h.x = f2bf(v.x); h.y = f2bf(v.y); h.z = f2bf(v.z); h.w = f2bf(v.w);
    ((ushort4*)x_a)[i] = h;
}

// ---------------------------------------------------------------------------
// Partition: one block per chunk. LDS histogram -> shuffle scan (2 barriers)
// -> coalesced directory write -> ranked chunk-local bucket-sorted payload.
// Payload: int2{ (row_local<<18)|col , val_bits }.
// ---------------------------------------------------------------------------
__global__ void __launch_bounds__(PART_T)
part_kernel(const int* __restrict__ rows,
            const int* __restrict__ cols,
            const float* __restrict__ vals,
            int* __restrict__ runstart,
            int2* __restrict__ bucket_ev) {
    __shared__ int hist[NB];
    __shared__ int wsum[16];
    const int tid   = threadIdx.x;
    const int chunk = blockIdx.x;
    const int e0    = chunk * CH;
    const int ecnt  = (N_EDGES - e0 < CH) ? (N_EDGES - e0) : CH;
    const int lane  = tid & 63, wid = tid >> 6;

    hist[tid] = 0;
    __syncthreads();

    int myrow[32];
    #pragma unroll
    for (int j = 0; j < 32; ++j) {
        int idx = j * PART_T + tid;
        int r = (idx < ecnt) ? rows[e0 + idx] : -1;
        myrow[j] = r;
        if (r >= 0) atomicAdd(&hist[(unsigned)r / RPB], 1);
    }
    __syncthreads();

    // shuffle-based inclusive scan over 1024 bins
    int v = hist[tid];
    int inc = v;
    #pragma unroll
    for (int off = 1; off < 64; off <<= 1) {
        int t = __shfl_up(inc, off, 64);
        if (lane >= off) inc += t;
    }
    if (lane == 63) wsum[wid] = inc;
    __syncthreads();
    if (wid == 0) {
        int s = (lane < 16) ? wsum[lane] : 0;
        #pragma unroll
        for (int off = 1; off < 16; off <<= 1) {
            int t = __shfl_up(s, off, 64);
            if (lane >= off) s += t;
        }
        if (lane < 16) wsum[lane] = s;
    }
    __syncthreads();
    int base = (wid > 0) ? wsum[wid - 1] : 0;
    int incl = base + inc;
    int excl = incl - v;
    runstart[(size_t)chunk * RS_LD + tid] = e0 + excl;        // coalesced
    if (tid == NB - 1) runstart[(size_t)chunk * RS_LD + NB] = e0 + incl;
    hist[tid] = excl;            // becomes cursor
    __syncthreads();

    #pragma unroll
    for (int j = 0; j < 32; ++j) {
        int r = myrow[j];
        if (r < 0) continue;
        int idx = j * PART_T + tid;
        unsigned b = (unsigned)r / RPB;
        int k = atomicAdd(&hist[b], 1);
        int2 ev;
        ev.x = (int)(((unsigned)(r - (int)b * RPB) << 18) | (unsigned)cols[e0 + idx]);
        ev.y = __float_as_int(vals[e0 + idx]);
        bucket_ev[e0 + k] = ev;
    }
}

// ---------------------------------------------------------------------------
// Bucket totals: partial sums over chunk-strides (coalesced), then 1-block
// shuffle scan -> bcsr (CSR base per bucket) + row_ptr[N_NODES].
// ---------------------------------------------------------------------------
__global__ void btot_kernel(const int* __restrict__ runstart, int* __restrict__ partial) {
    const int b = threadIdx.x;
    const int g = blockIdx.x;
    int c = 0;
    for (int ch = g; ch < N_PBLK; ch += NRED)
        c += runstart[(size_t)ch * RS_LD + b + 1] - runstart[(size_t)ch * RS_LD + b];
    partial[g * NB + b] = c;
}

__global__ void bscan_kernel(const int* __restrict__ partial,
                             int* __restrict__ bcsr,
                             int* __restrict__ row_ptr) {
    __shared__ int wsum[16];
    const int tid = threadIdx.x;
    const int lane = tid & 63, wid = tid >> 6;
    int v = 0;
    #pragma unroll
    for (int g = 0; g < NRED; ++g) v += partial[g * NB + tid];
    int inc = v;
    #pragma unroll
    for (int off = 1; off < 64; off <<= 1) {
        int t = __shfl_up(inc, off, 64);
        if (lane >= off) inc += t;
    }
    if (lane == 63) wsum[wid] = inc;
    __syncthreads();
    if (wid == 0) {
        int s = (lane < 16) ? wsum[lane] : 0;
        #pragma unroll
        for (int off = 1; off < 16; off <<= 1) {
            int t = __shfl_up(s, off, 64);
            if (lane >= off) s += t;
        }
        if (lane < 16) wsum[lane] = s;
    }
    __syncthreads();
    int base = (wid > 0) ? wsum[wid - 1] : 0;
    bcsr[tid] = base + inc - v;          // exclusive
    if (tid == 0) row_ptr[N_NODES] = N_EDGES;
}

// ---------------------------------------------------------------------------
// Mini-scatter: one block (512 thr) per bucket. Counts its 147 rows over the
// 245 runs, shuffle scan -> row_ptr + LDS cursors, then scatter -> row-sorted
// CSR confined to the bucket's span.
// ---------------------------------------------------------------------------
__global__ void __launch_bounds__(MS_T)
mini_scatter_kernel(const int* __restrict__ runstart,
                    const int2* __restrict__ bucket_ev,
                    const int* __restrict__ bcsr,
                    int* __restrict__ row_ptr,
                    int2* __restrict__ csr_ev) {
    __shared__ int rs0[N_PBLK];
    __shared__ int rs1[N_PBLK];
    __shared__ int cnt_r[RPB];
    __shared__ int cur[RPB];
    __shared__ int wsum[MS_T / 64];
    const int b   = blockIdx.x;
    const int tid = threadIdx.x;
    const int lane = tid & 63, wid = tid >> 6;

    for (int i = tid; i < N_PBLK; i += MS_T) {
        rs0[i] = runstart[(size_t)i * RS_LD + b];
        rs1[i] = runstart[(size_t)i * RS_LD + b + 1];
    }
    if (tid < RPB) cnt_r[tid] = 0;
    __syncthreads();

    const int hw = tid >> 5, ln = tid & 31;
    for (int c = hw; c < N_PBLK; c += (MS_T / 32))
        for (int i = rs0[c] + ln; i < rs1[c]; i += 32)
            atomicAdd(&cnt_r[(unsigned)bucket_ev[i].x >> 18], 1);
    __syncthreads();

    int v = (tid < RPB) ? cnt_r[tid] : 0;
    int inc = v;
    #pragma unroll
    for (int off = 1; off < 64; off <<= 1) {
        int t = __shfl_up(inc, off, 64);
        if (lane >= off) inc += t;
    }
    if (lane == 63) wsum[wid] = inc;
    __syncthreads();
    if (wid == 0) {
        int s = (lane < MS_T / 64) ? wsum[lane] : 0;
        #pragma unroll
        for (int off = 1; off < MS_T / 64; off <<= 1) {
            int t = __shfl_up(s, off, 64);
            if (lane >= off) s += t;
        }
        if (lane < MS_T / 64) wsum[lane] = s;
    }
    __syncthreads();
    const int cb = bcsr[b];
    if (tid < RPB) {
        int base = (wid > 0) ? wsum[wid - 1] : 0;
        int excl = cb + base + inc - v;
        cur[tid] = excl;
        int r = b * RPB + tid;
        if (r < N_NODES) row_ptr[r] = excl;
    }
    __syncthreads();

    for (int c = hw; c < N_PBLK; c += (MS_T / 32))
        for (int i = rs0[c] + ln; i < rs1[c]; i += 32) {
            int2 ev = bucket_ev[i];
            unsigned key = (unsigned)ev.x;
            int pos = atomicAdd(&cur[key >> 18], 1);
            int2 o; o.x = (int)(key & 0x3FFFFu); o.y = ev.y;
            csr_ev[pos] = o;
        }
}

// ---------------------------------------------------------------------------
// CSR SpMM, bf16 gather, f32 accumulate. Half-wave per row, lane = dim.
// Fused: emb_sum += acc; xout(bf16) stored unless last layer.
// ---------------------------------------------------------------------------
__global__ void spmm_kernel(const int* __restrict__ row_ptr,
                            const int2* __restrict__ csr_ev,
                            const unsigned short* __restrict__ xin,
                            unsigned short* __restrict__ xout,
                            float* __restrict__ emb_sum,
                            int write_x) {
    int tid = blockIdx.x * blockDim.x + threadIdx.x;
    int row = tid >> 5;
    int d   = tid & 31;
    if (row >= N_NODES) return;
    int s = row_ptr[row];
    int e = row_ptr[row + 1];
    float acc = 0.f;
    int i = s;
    for (; i + 8 <= e; i += 8) {
        int2 ev[8];
        #pragma unroll
        for (int j = 0; j < 8; ++j) ev[j] = csr_ev[i + j];
        float x[8];
        #pragma unroll
        for (int j = 0; j < 8; ++j)
            x[j] = bf2f(xin[(unsigned)ev[j].x * DIM + d]);
        #pragma unroll
        for (int j = 0; j < 8; ++j)
            acc += __int_as_float(ev[j].y) * x[j];
    }
    for (; i < e; ++i) {
        int2 ev = csr_ev[i];
        acc += __int_as_float(ev.y) * bf2f(xin[(unsigned)ev.x * DIM + d]);
    }
    int o = row * DIM + d;
    if (write_x) xout[o] = f2bf(acc);
    emb_sum[o] += acc;
}

// ---------------------------------------------------------------------------
// Readout.
// ---------------------------------------------------------------------------
__global__ void final_kernel(const int* __restrict__ users,
                             const int* __restrict__ items,
                             const float* __restrict__ emb_sum,
                             const float* __restrict__ means,
                             const float* __restrict__ stds,
                             float* __restrict__ out) {
    int b = blockIdx.x * blockDim.x + threadIdx.x;
    if (b >= B_OUT) return;
    int u  = users[b];
    int it = items[b] + N_USERS;
    const float4* su = (const float4*)(emb_sum + (size_t)u  * DIM);
    const float4* si = (const float4*)(emb_sum + (size_t)it * DIM);
    float gamma = 0.f;
    #pragma unroll
    for (int k = 0; k < DIM / 4; ++k) {
        float4 a = su[k], c = si[k];
        gamma += (a.x * 0.25f) * (c.x * 0.25f) + (a.y * 0.25f) * (c.y * 0.25f)
               + (a.z * 0.25f) * (c.z * 0.25f) + (a.w * 0.25f) * (c.w * 0.25f);
    }
    out[b] = gamma * stds[u] + means[u];
}

extern "C" void kernel_launch(void* const* d_in, const int* in_sizes, int n_in,
                              void* d_out, int out_size, void* d_ws, size_t ws_size,
                              hipStream_t stream) {
    const int*   users    = (const int*)d_in[0];
    const int*   items    = (const int*)d_in[1];
    const int*   rows     = (const int*)d_in[2];
    const int*   cols     = (const int*)d_in[3];
    const float* vals     = (const float*)d_in[4];
    const float* user_emb = (const float*)d_in[5];
    const float* item_emb = (const float*)d_in[6];
    const float* means    = (const float*)d_in[7];
    const float* stds     = (const float*)d_in[8];
    float* out = (float*)d_out;

    char* w = (char*)d_ws;
    size_t off = 0;
    auto alloc = [&](size_t bytes) -> void* {
        void* p = w + off;
        off = (off + bytes + 255) & ~(size_t)255;
        return p;
    };
    // Region A: bucket_ev (live: part -> mini_scatter) aliases
    //           {x_a, x_b, emb_sum} (live: init -> end).
    size_t regionA = ((size_t)N_PBLK * CH * sizeof(int2) + 255) & ~(size_t)255;  // 64.2 MB
    char* a0 = (char*)alloc(regionA);
    int2* bucket_ev = (int2*)a0;
    size_t aoff = 0;
    auto allocA = [&](size_t bytes) -> void* {
        void* p = a0 + aoff;
        aoff = (aoff + bytes + 255) & ~(size_t)255;
        return p;
    };
    unsigned short* x_a     = (unsigned short*)allocA((size_t)N_NODES * DIM * 2);  // 9.6 MB
    unsigned short* x_b     = (unsigned short*)allocA((size_t)N_NODES * DIM * 2);  // 9.6 MB
    float*          emb_sum = (float*)allocA((size_t)N_NODES * DIM * 4);           // 19.2 MB

    int*  runstart = (int*) alloc((size_t)N_PBLK * RS_LD * sizeof(int));       // 1.0 MB
    int*  partial  = (int*) alloc((size_t)NRED * NB * sizeof(int));
    int*  row_ptr  = (int*) alloc((size_t)(N_NODES + 1) * sizeof(int));
    int*  bcsr     = (int*) alloc((size_t)NB * sizeof(int));
    int2* csr_ev   = (int2*)alloc((size_t)N_EDGES * sizeof(int2));              // 64 MB
    (void)ws_size;

    const int g_init  = (N_NODES * DIM / 4 + T - 1) / T;
    const int g_spmm  = (N_NODES * DIM + T - 1) / T;     // 18750
    const int g_final = (B_OUT + T - 1) / T;

    // --- CSR build ---
    part_kernel<<<N_PBLK, PART_T, 0, stream>>>(rows, cols, vals, runstart, bucket_ev);
    btot_kernel<<<NRED, NB, 0, stream>>>(runstart, partial);
    bscan_kernel<<<1, NB, 0, stream>>>(partial, bcsr, row_ptr);
    mini_scatter_kernel<<<NB, MS_T, 0, stream>>>(runstart, bucket_ev, bcsr, row_ptr, csr_ev);

    // --- dense pipeline (bucket_ev dead from here; region reused) ---
    init_kernel<<<g_init, T, 0, stream>>>(user_emb, item_emb, x_a, emb_sum);
    spmm_kernel<<<g_spmm, T, 0, stream>>>(row_ptr, csr_ev, x_a, x_b, emb_sum, 1);
    spmm_kernel<<<g_spmm, T, 0, stream>>>(row_ptr, csr_ev, x_b, x_a, emb_sum, 1);
    spmm_kernel<<<g_spmm, T, 0, stream>>>(row_ptr, csr_ev, x_a, x_b, emb_sum, 0);

    final_kernel<<<g_final, T, 0, stream>>>(users, items, emb_sum, means, stds, out);
}

// Round 8
// 504.287 us; speedup vs baseline: 8.0236x; 1.0741x over previous
//
#include <hip/hip_runtime.h>

#define N_USERS 100000
#define N_ITEMS 50000
#define N_NODES 150000
#define DIM 32
#define N_EDGES 8000000
#define B_OUT 65536

#define NB 1024                      // row buckets
#define RPB 147                      // rows per bucket (1024*147 >= 150000)
#define CH 16384                     // edges per chunk (payload fits LDS)
#define N_PBLK ((N_EDGES + CH - 1) / CH)   // 489
#define PART_T 1024
#define EPT (CH / PART_T)            // 16 edges per thread
#define MS_T 512
#define T 256
#define NRED 8                       // partial-reduce blocks for bucket totals
#define RS_LD (NB + 1)               // runstart leading dim: [chunk][NB+1]

__device__ __forceinline__ unsigned short f2bf(float f) {
    unsigned b = __float_as_uint(f);
    return (unsigned short)((b + 0x7FFFu + ((b >> 16) & 1u)) >> 16);   // RNE
}
__device__ __forceinline__ float bf2f(unsigned short u) {
    return __uint_as_float((unsigned)u << 16);
}

// ---------------------------------------------------------------------------
// init: x_a(bf16) = concat(user_emb, item_emb); emb_sum(f32) = same.
// ---------------------------------------------------------------------------
__global__ void init_kernel(const float* __restrict__ user_emb,
                            const float* __restrict__ item_emb,
                            unsigned short* __restrict__ x_a,
                            float* __restrict__ emb_sum) {
    int i = blockIdx.x * blockDim.x + threadIdx.x;   // float4 index
    const int total = N_NODES * DIM / 4;
    if (i >= total) return;
    const int user_f4 = N_USERS * DIM / 4;
    float4 v;
    if (i < user_f4) v = ((const float4*)user_emb)[i];
    else             v = ((const float4*)item_emb)[i - user_f4];
    ((float4*)emb_sum)[i] = v;
    ushort4 h;
    h.x = f2bf(v.x); h.y = f2bf(v.y); h.z = f2bf(v.z); h.w = f2bf(v.w);
    ((ushort4*)x_a)[i] = h;
}

// ---------------------------------------------------------------------------
// Partition: one block per 16K-edge chunk. LDS histogram -> shuffle scan ->
// rank into LDS payload buffer -> STREAM out (coalesced int4).
// Global writes are exactly sequential: 66 MB total.
// Payload: int2{ (row_local<<18)|col , val_bits }.
// ---------------------------------------------------------------------------
__global__ void __launch_bounds__(PART_T)
part_kernel(const int* __restrict__ rows,
            const int* __restrict__ cols,
            const float* __restrict__ vals,
            int* __restrict__ runstart,
            int2* __restrict__ bucket_ev) {
    __shared__ int2 buf[CH];         // 128 KB staged payload
    __shared__ int hist[NB];         // 4 KB
    __shared__ int wsum[16];
    const int tid   = threadIdx.x;
    const int chunk = blockIdx.x;
    const int e0    = chunk * CH;
    const int ecnt  = (N_EDGES - e0 < CH) ? (N_EDGES - e0) : CH;
    const int lane  = tid & 63, wid = tid >> 6;

    hist[tid] = 0;
    __syncthreads();

    int myrow[EPT];
    #pragma unroll
    for (int j = 0; j < EPT; ++j) {
        int idx = j * PART_T + tid;
        int r = (idx < ecnt) ? rows[e0 + idx] : -1;
        myrow[j] = r;
        if (r >= 0) atomicAdd(&hist[(unsigned)r / RPB], 1);
    }
    __syncthreads();

    // shuffle-based inclusive scan over 1024 bins
    int v = hist[tid];
    int inc = v;
    #pragma unroll
    for (int off = 1; off < 64; off <<= 1) {
        int t = __shfl_up(inc, off, 64);
        if (lane >= off) inc += t;
    }
    if (lane == 63) wsum[wid] = inc;
    __syncthreads();
    if (wid == 0) {
        int s = (lane < 16) ? wsum[lane] : 0;
        #pragma unroll
        for (int off = 1; off < 16; off <<= 1) {
            int t = __shfl_up(s, off, 64);
            if (lane >= off) s += t;
        }
        if (lane < 16) wsum[lane] = s;
    }
    __syncthreads();
    int base = (wid > 0) ? wsum[wid - 1] : 0;
    int incl = base + inc;
    int excl = incl - v;
    runstart[(size_t)chunk * RS_LD + tid] = e0 + excl;        // coalesced
    if (tid == NB - 1) runstart[(size_t)chunk * RS_LD + NB] = e0 + incl;
    hist[tid] = excl;            // becomes cursor
    __syncthreads();

    // rank into LDS payload buffer
    #pragma unroll
    for (int j = 0; j < EPT; ++j) {
        int r = myrow[j];
        if (r < 0) continue;
        int idx = j * PART_T + tid;
        unsigned b = (unsigned)r / RPB;
        int k = atomicAdd(&hist[b], 1);
        int2 ev;
        ev.x = (int)(((unsigned)(r - (int)b * RPB) << 18) | (unsigned)cols[e0 + idx]);
        ev.y = __float_as_int(vals[e0 + idx]);
        buf[k] = ev;
    }
    __syncthreads();

    // stream out, coalesced 16B stores (ecnt is always even)
    const int n4 = ecnt >> 1;
    const int4* b4 = (const int4*)buf;
    int4* g4 = (int4*)(bucket_ev + e0);
    for (int i = tid; i < n4; i += PART_T) g4[i] = b4[i];
}

// ---------------------------------------------------------------------------
// Bucket totals: partial sums over chunk-strides (coalesced), then 1-block
// shuffle scan -> bcsr (CSR base per bucket) + row_ptr[N_NODES].
// ---------------------------------------------------------------------------
__global__ void btot_kernel(const int* __restrict__ runstart, int* __restrict__ partial) {
    const int b = threadIdx.x;
    const int g = blockIdx.x;
    int c = 0;
    for (int ch = g; ch < N_PBLK; ch += NRED)
        c += runstart[(size_t)ch * RS_LD + b + 1] - runstart[(size_t)ch * RS_LD + b];
    partial[g * NB + b] = c;
}

__global__ void bscan_kernel(const int* __restrict__ partial,
                             int* __restrict__ bcsr,
                             int* __restrict__ row_ptr) {
    __shared__ int wsum[16];
    const int tid = threadIdx.x;
    const int lane = tid & 63, wid = tid >> 6;
    int v = 0;
    #pragma unroll
    for (int g = 0; g < NRED; ++g) v += partial[g * NB + tid];
    int inc = v;
    #pragma unroll
    for (int off = 1; off < 64; off <<= 1) {
        int t = __shfl_up(inc, off, 64);
        if (lane >= off) inc += t;
    }
    if (lane == 63) wsum[wid] = inc;
    __syncthreads();
    if (wid == 0) {
        int s = (lane < 16) ? wsum[lane] : 0;
        #pragma unroll
        for (int off = 1; off < 16; off <<= 1) {
            int t = __shfl_up(s, off, 64);
            if (lane >= off) s += t;
        }
        if (lane < 16) wsum[lane] = s;
    }
    __syncthreads();
    int base = (wid > 0) ? wsum[wid - 1] : 0;
    bcsr[tid] = base + inc - v;          // exclusive
    if (tid == 0) row_ptr[N_NODES] = N_EDGES;
}

// ---------------------------------------------------------------------------
// Mini-scatter: one block (512 thr) per bucket. Counts its 147 rows over the
// 489 runs (16-lane groups matching avg run length 16), shuffle scan ->
// row_ptr + LDS cursors, then scatter -> row-sorted CSR in the bucket's span.
// ---------------------------------------------------------------------------
__global__ void __launch_bounds__(MS_T)
mini_scatter_kernel(const int* __restrict__ runstart,
                    const int2* __restrict__ bucket_ev,
                    const int* __restrict__ bcsr,
                    int* __restrict__ row_ptr,
                    int2* __restrict__ csr_ev) {
    __shared__ int rs0[N_PBLK];
    __shared__ int rs1[N_PBLK];
    __shared__ int cnt_r[RPB];
    __shared__ int cur[RPB];
    __shared__ int wsum[MS_T / 64];
    const int b   = blockIdx.x;
    const int tid = threadIdx.x;
    const int lane = tid & 63, wid = tid >> 6;

    for (int i = tid; i < N_PBLK; i += MS_T) {
        rs0[i] = runstart[(size_t)i * RS_LD + b];
        rs1[i] = runstart[(size_t)i * RS_LD + b + 1];
    }
    if (tid < RPB) cnt_r[tid] = 0;
    __syncthreads();

    const int grp = tid >> 4, ln = tid & 15;     // 16-lane groups
    for (int c = grp; c < N_PBLK; c += (MS_T / 16))
        for (int i = rs0[c] + ln; i < rs1[c]; i += 16)
            atomicAdd(&cnt_r[(unsigned)bucket_ev[i].x >> 18], 1);
    __syncthreads();

    int v = (tid < RPB) ? cnt_r[tid] : 0;
    int inc = v;
    #pragma unroll
    for (int off = 1; off < 64; off <<= 1) {
        int t = __shfl_up(inc, off, 64);
        if (lane >= off) inc += t;
    }
    if (lane == 63) wsum[wid] = inc;
    __syncthreads();
    if (wid == 0) {
        int s = (lane < MS_T / 64) ? wsum[lane] : 0;
        #pragma unroll
        for (int off = 1; off < MS_T / 64; off <<= 1) {
            int t = __shfl_up(s, off, 64);
            if (lane >= off) s += t;
        }
        if (lane < MS_T / 64) wsum[lane] = s;
    }
    __syncthreads();
    const int cb = bcsr[b];
    if (tid < RPB) {
        int base = (wid > 0) ? wsum[wid - 1] : 0;
        int excl = cb + base + inc - v;
        cur[tid] = excl;
        int r = b * RPB + tid;
        if (r < N_NODES) row_ptr[r] = excl;
    }
    __syncthreads();

    for (int c = grp; c < N_PBLK; c += (MS_T / 16))
        for (int i = rs0[c] + ln; i < rs1[c]; i += 16) {
            int2 ev = bucket_ev[i];
            unsigned key = (unsigned)ev.x;
            int pos = atomicAdd(&cur[key >> 18], 1);
            int2 o; o.x = (int)(key & 0x3FFFFu); o.y = ev.y;
            csr_ev[pos] = o;
        }
}

// ---------------------------------------------------------------------------
// CSR SpMM, bf16 gather, f32 accumulate. Half-wave per row, lane = dim.
// Fused: emb_sum += acc; xout(bf16) stored unless last layer.
// ---------------------------------------------------------------------------
__global__ void spmm_kernel(const int* __restrict__ row_ptr,
                            const int2* __restrict__ csr_ev,
                            const unsigned short* __restrict__ xin,
                            unsigned short* __restrict__ xout,
                            float* __restrict__ emb_sum,
                            int write_x) {
    int tid = blockIdx.x * blockDim.x + threadIdx.x;
    int row = tid >> 5;
    int d   = tid & 31;
    if (row >= N_NODES) return;
    int s = row_ptr[row];
    int e = row_ptr[row + 1];
    float acc = 0.f;
    int i = s;
    for (; i + 8 <= e; i += 8) {
        int2 ev[8];
        #pragma unroll
        for (int j = 0; j < 8; ++j) ev[j] = csr_ev[i + j];
        float x[8];
        #pragma unroll
        for (int j = 0; j < 8; ++j)
            x[j] = bf2f(xin[(unsigned)ev[j].x * DIM + d]);
        #pragma unroll
        for (int j = 0; j < 8; ++j)
            acc += __int_as_float(ev[j].y) * x[j];
    }
    for (; i < e; ++i) {
        int2 ev = csr_ev[i];
        acc += __int_as_float(ev.y) * bf2f(xin[(unsigned)ev.x * DIM + d]);
    }
    int o = row * DIM + d;
    if (write_x) xout[o] = f2bf(acc);
    emb_sum[o] += acc;
}

// ---------------------------------------------------------------------------
// Readout.
// ---------------------------------------------------------------------------
__global__ void final_kernel(const int* __restrict__ users,
                             const int* __restrict__ items,
                             const float* __restrict__ emb_sum,
                             const float* __restrict__ means,
                             const float* __restrict__ stds,
                             float* __restrict__ out) {
    int b = blockIdx.x * blockDim.x + threadIdx.x;
    if (b >= B_OUT) return;
    int u  = users[b];
    int it = items[b] + N_USERS;
    const float4* su = (const float4*)(emb_sum + (size_t)u  * DIM);
    const float4* si = (const float4*)(emb_sum + (size_t)it * DIM);
    float gamma = 0.f;
    #pragma unroll
    for (int k = 0; k < DIM / 4; ++k) {
        float4 a = su[k], c = si[k];
        gamma += (a.x * 0.25f) * (c.x * 0.25f) + (a.y * 0.25f) * (c.y * 0.25f)
               + (a.z * 0.25f) * (c.z * 0.25f) + (a.w * 0.25f) * (c.w * 0.25f);
    }
    out[b] = gamma * stds[u] + means[u];
}

extern "C" void kernel_launch(void* const* d_in, const int* in_sizes, int n_in,
                              void* d_out, int out_size, void* d_ws, size_t ws_size,
                              hipStream_t stream) {
    const int*   users    = (const int*)d_in[0];
    const int*   items    = (const int*)d_in[1];
    const int*   rows     = (const int*)d_in[2];
    const int*   cols     = (const int*)d_in[3];
    const float* vals     = (const float*)d_in[4];
    const float* user_emb = (const float*)d_in[5];
    const float* item_emb = (const float*)d_in[6];
    const float* means    = (const float*)d_in[7];
    const float* stds     = (const float*)d_in[8];
    float* out = (float*)d_out;

    char* w = (char*)d_ws;
    size_t off = 0;
    auto alloc = [&](size_t bytes) -> void* {
        void* p = w + off;
        off = (off + bytes + 255) & ~(size_t)255;
        return p;
    };
    // Region A: bucket_ev (live: part -> mini_scatter) aliases
    //           {x_a, x_b, emb_sum} (live: init -> end).
    size_t regionA = ((size_t)N_PBLK * CH * sizeof(int2) + 255) & ~(size_t)255;  // 64.1 MB
    char* a0 = (char*)alloc(regionA);
    int2* bucket_ev = (int2*)a0;
    size_t aoff = 0;
    auto allocA = [&](size_t bytes) -> void* {
        void* p = a0 + aoff;
        aoff = (aoff + bytes + 255) & ~(size_t)255;
        return p;
    };
    unsigned short* x_a     = (unsigned short*)allocA((size_t)N_NODES * DIM * 2);  // 9.6 MB
    unsigned short* x_b     = (unsigned short*)allocA((size_t)N_NODES * DIM * 2);  // 9.6 MB
    float*          emb_sum = (float*)allocA((size_t)N_NODES * DIM * 4);           // 19.2 MB

    int*  runstart = (int*) alloc((size_t)N_PBLK * RS_LD * sizeof(int));       // 2.0 MB
    int*  partial  = (int*) alloc((size_t)NRED * NB * sizeof(int));
    int*  row_ptr  = (int*) alloc((size_t)(N_NODES + 1) * sizeof(int));
    int*  bcsr     = (int*) alloc((size_t)NB * sizeof(int));
    int2* csr_ev   = (int2*)alloc((size_t)N_EDGES * sizeof(int2));              // 64 MB
    (void)ws_size;

    const int g_init  = (N_NODES * DIM / 4 + T - 1) / T;
    const int g_spmm  = (N_NODES * DIM + T - 1) / T;     // 18750
    const int g_final = (B_OUT + T - 1) / T;

    // --- CSR build ---
    part_kernel<<<N_PBLK, PART_T, 0, stream>>>(rows, cols, vals, runstart, bucket_ev);
    btot_kernel<<<NRED, NB, 0, stream>>>(runstart, partial);
    bscan_kernel<<<1, NB, 0, stream>>>(partial, bcsr, row_ptr);
    mini_scatter_kernel<<<NB, MS_T, 0, stream>>>(runstart, bucket_ev, bcsr, row_ptr, csr_ev);

    // --- dense pipeline (bucket_ev dead from here; region reused) ---
    init_kernel<<<g_init, T, 0, stream>>>(user_emb, item_emb, x_a, emb_sum);
    spmm_kernel<<<g_spmm, T, 0, stream>>>(row_ptr, csr_ev, x_a, x_b, emb_sum, 1);
    spmm_kernel<<<g_spmm, T, 0, stream>>>(row_ptr, csr_ev, x_b, x_a, emb_sum, 1);
    spmm_kernel<<<g_spmm, T, 0, stream>>>(row_ptr, csr_ev, x_a, x_b, emb_sum, 0);

    final_kernel<<<g_final, T, 0, stream>>>(users, items, emb_sum, means, stds, out);
}